// Round 1
// baseline (182.962 us; speedup 1.0000x reference)
//
#include <hip/hip_runtime.h>

#define N_ROWS 300000
#define FIN    128
#define HDIM   64
#define ODIM   32
#define KREL   5
#define BR     64
#define NTILES ((N_ROWS + BR - 1) / BR + KREL)   // 4693
#define NB     (NTILES * BR)

typedef __attribute__((ext_vector_type(8))) short bf8_t;   // 8 bf16 = 4 VGPR
typedef __attribute__((ext_vector_type(4))) float f32x4;

static __device__ __forceinline__ unsigned short f2bf(float f) {
  unsigned int u = __float_as_uint(f);
  return (unsigned short)((u + 0x7FFFu + ((u >> 16) & 1u)) >> 16);   // RNE
}

static __device__ __forceinline__ bf8_t lds_load16(const void* base, int byte) {
  return *(const bf8_t*)((const char*)base + byte);
}

static __device__ __forceinline__ void stbf4(void* base, int byte, float4 v) {
  unsigned long long p = (unsigned long long)f2bf(v.x)
                       | ((unsigned long long)f2bf(v.y) << 16)
                       | ((unsigned long long)f2bf(v.z) << 32)
                       | ((unsigned long long)f2bf(v.w) << 48);
  *(unsigned long long*)((char*)base + byte) = p;
}

// ---------------- bucketing ----------------

__global__ void hist_kernel(const int* __restrict__ r, int* __restrict__ cnt) {
  __shared__ int lc[KREL];
  int tid = threadIdx.x;
  if (tid < KREL) lc[tid] = 0;
  __syncthreads();
  int i = blockIdx.x * blockDim.x + tid;
  if (i < N_ROWS) atomicAdd(&lc[r[i]], 1);
  __syncthreads();
  if (tid < KREL && lc[tid]) atomicAdd(&cnt[tid], lc[tid]);
}

__global__ void offs_kernel(const int* __restrict__ cnt, int* __restrict__ aoff,
                            int* __restrict__ cursor) {
  int off = 0;
  for (int k = 0; k < KREL; ++k) {
    aoff[k] = off;
    cursor[k] = off;
    off += ((cnt[k] + BR - 1) / BR) * BR;
  }
  aoff[KREL] = off;
}

__global__ void scat_kernel(const int* __restrict__ r, int* __restrict__ bucket,
                            int* __restrict__ cursor) {
  __shared__ int lc[KREL];
  __shared__ int base[KREL];
  int tid = threadIdx.x;
  if (tid < KREL) lc[tid] = 0;
  __syncthreads();
  int i = blockIdx.x * blockDim.x + tid;
  int k = 0, lr = 0;
  if (i < N_ROWS) { k = r[i]; lr = atomicAdd(&lc[k], 1); }
  __syncthreads();
  if (tid < KREL) base[tid] = lc[tid] ? atomicAdd(&cursor[tid], lc[tid]) : 0;
  __syncthreads();
  if (i < N_ROWS) bucket[base[k] + lr] = i;
}

// ---------------- main fused kernel ----------------

__global__ __launch_bounds__(256) void gcn_main(
    const float* __restrict__ user, const float* __restrict__ item,
    const float* __restrict__ c,
    const float* __restrict__ Wu, const float* __restrict__ bu,
    const float* __restrict__ Wv, const float* __restrict__ bv,
    const float* __restrict__ Wl, const float* __restrict__ bl,
    const int* __restrict__ bucket, const int* __restrict__ aoff,
    float* __restrict__ out)
{
  __shared__ __align__(16) unsigned short sWu[HDIM * FIN];   // 16 KB, bf16 swizzled
  __shared__ __align__(16) unsigned short sWv[HDIM * FIN];
  __shared__ __align__(16) unsigned short sXu[BR * FIN];     // item rows (reused as Hu)
  __shared__ __align__(16) unsigned short sXv[BR * FIN];     // user rows (reused as Hv)
  __shared__ float sC[BR];
  __shared__ int   sIdx[BR];
  __shared__ float sBu[HDIM];
  __shared__ float sBv[HDIM];

  const int tid   = threadIdx.x;
  const int tile0 = blockIdx.x * BR;
  if (tile0 >= aoff[KREL]) return;

  int rel = 0;
  #pragma unroll
  for (int k = 0; k < KREL; ++k) if (tile0 >= aoff[k + 1]) rel = k + 1;

  // stage row indices / c / biases
  if (tid < BR) {
    int idx = bucket[tile0 + tid];
    sIdx[tid] = idx;
    sC[tid]   = (idx >= 0) ? c[idx] : 0.0f;
  }
  if (tid >= 192) {
    int h = tid - 192;
    sBu[h] = bu[rel * HDIM + h];
    sBv[h] = bv[rel * HDIM + h];
  }

  // stage relation weights -> bf16 LDS, XOR-swizzled rows (row stride 256 B)
  const float4* wu4 = (const float4*)(Wu + (size_t)rel * HDIM * FIN);
  const float4* wv4 = (const float4*)(Wv + (size_t)rel * HDIM * FIN);
  #pragma unroll
  for (int it = 0; it < 8; ++it) {
    int f4  = it * 256 + tid;        // 0..2047
    int row = f4 >> 5;               // 32 float4 per row
    int c4  = f4 & 31;
    int byte = (row * 256 + c4 * 8) ^ ((row & 7) << 4);
    stbf4(sWu, byte, wu4[f4]);
    stbf4(sWv, byte, wv4[f4]);
  }
  __syncthreads();   // sIdx ready

  // stage gathered X rows -> bf16 LDS (same swizzle)
  #pragma unroll
  for (int it = 0; it < 8; ++it) {
    int f4  = it * 256 + tid;
    int row = f4 >> 5;
    int c4  = f4 & 31;
    int idx = sIdx[row];
    float4 a = make_float4(0.f, 0.f, 0.f, 0.f);
    float4 b = a;
    if (idx >= 0) {
      a = *(const float4*)(item + (size_t)idx * FIN + c4 * 4);
      b = *(const float4*)(user + (size_t)idx * FIN + c4 * 4);
    }
    int byte = (row * 256 + c4 * 8) ^ ((row & 7) << 4);
    stbf4(sXu, byte, a);
    stbf4(sXv, byte, b);
  }
  __syncthreads();

  const int lane = tid & 63;
  const int wid  = tid >> 6;        // wave 0..3, owns rows [wid*16, wid*16+16)
  const int lrow = lane & 15;
  const int lkg  = lane >> 4;

  // layer-2 weight fragments (Wl[32][64] -> B frags), held in registers
  bf8_t wl[2][2];
  #pragma unroll
  for (int n2 = 0; n2 < 2; ++n2)
    #pragma unroll
    for (int k2 = 0; k2 < 2; ++k2) {
      const float* p = Wl + (size_t)(n2 * 16 + lrow) * HDIM + k2 * 32 + lkg * 8;
      bf8_t f;
      #pragma unroll
      for (int j = 0; j < 8; ++j) f[j] = (short)f2bf(p[j]);
      wl[n2][k2] = f;
    }
  const float blv0 = bl[lrow];
  const float blv1 = bl[16 + lrow];

  // ---- layer 1: [64 rows] x [64 h], K = 128 ----
  f32x4 accU[4], accV[4];
  #pragma unroll
  for (int n = 0; n < 4; ++n) {
    accU[n] = f32x4{0.f, 0.f, 0.f, 0.f};
    accV[n] = f32x4{0.f, 0.f, 0.f, 0.f};
  }

  const int arow = wid * 16 + lrow;
  const int axor = (arow & 7) << 4;
  #pragma unroll
  for (int kc = 0; kc < 4; ++kc) {
    const int kb = (kc * 32 + lkg * 8) * 2;   // byte offset within 256 B row
    bf8_t au = lds_load16(sXu, (arow * 256 + kb) ^ axor);
    bf8_t av = lds_load16(sXv, (arow * 256 + kb) ^ axor);
    #pragma unroll
    for (int n = 0; n < 4; ++n) {
      int brow = n * 16 + lrow;
      int bx   = (brow * 256 + kb) ^ ((brow & 7) << 4);
      bf8_t fu = lds_load16(sWu, bx);
      bf8_t fv = lds_load16(sWv, bx);
      accU[n] = __builtin_amdgcn_mfma_f32_16x16x32_bf16(au, fu, accU[n], 0, 0, 0);
      accV[n] = __builtin_amdgcn_mfma_f32_16x16x32_bf16(av, fv, accV[n], 0, 0, 0);
    }
  }
  __syncthreads();   // all X reads done; H will alias X space

  // epilogue 1: H = relu(c * (acc + b)) -> bf16 LDS [64][64], row stride 128 B, swizzled
  unsigned short* sHu = sXu;
  unsigned short* sHv = sXv;
  #pragma unroll
  for (int n = 0; n < 4; ++n) {
    int hcol = n * 16 + lrow;
    float bU = sBu[hcol], bV = sBv[hcol];
    #pragma unroll
    for (int q = 0; q < 4; ++q) {
      int rr = wid * 16 + lkg * 4 + q;
      float cc = sC[rr];
      int byte = (rr * 128 + hcol * 2) ^ ((rr & 7) << 4);
      *(unsigned short*)((char*)sHu + byte) = f2bf(fmaxf(cc * (accU[n][q] + bU), 0.f));
      *(unsigned short*)((char*)sHv + byte) = f2bf(fmaxf(cc * (accV[n][q] + bV), 0.f));
    }
  }
  __syncthreads();

  // ---- layer 2: [64 rows] x [32 o], K = 64 ----
  f32x4 accOU[2], accOV[2];
  #pragma unroll
  for (int n2 = 0; n2 < 2; ++n2) {
    accOU[n2] = f32x4{0.f, 0.f, 0.f, 0.f};
    accOV[n2] = f32x4{0.f, 0.f, 0.f, 0.f};
  }
  #pragma unroll
  for (int k2 = 0; k2 < 2; ++k2) {
    const int kb = (k2 * 32 + lkg * 8) * 2;   // byte offset within 128 B row
    bf8_t a2u = lds_load16(sHu, (arow * 128 + kb) ^ axor);
    bf8_t a2v = lds_load16(sHv, (arow * 128 + kb) ^ axor);
    #pragma unroll
    for (int n2 = 0; n2 < 2; ++n2) {
      accOU[n2] = __builtin_amdgcn_mfma_f32_16x16x32_bf16(a2u, wl[n2][k2], accOU[n2], 0, 0, 0);
      accOV[n2] = __builtin_amdgcn_mfma_f32_16x16x32_bf16(a2v, wl[n2][k2], accOV[n2], 0, 0, 0);
    }
  }

  // epilogue 2: out = relu(acc + bl), scattered row stores
  #pragma unroll
  for (int n2 = 0; n2 < 2; ++n2) {
    int col = n2 * 16 + lrow;
    float bb = (n2 == 0) ? blv0 : blv1;
    #pragma unroll
    for (int q = 0; q < 4; ++q) {
      int rr  = wid * 16 + lkg * 4 + q;
      int idx = sIdx[rr];
      if (idx >= 0) {
        out[(size_t)idx * ODIM + col]            = fmaxf(accOU[n2][q] + bb, 0.f);
        out[(size_t)(N_ROWS + idx) * ODIM + col] = fmaxf(accOV[n2][q] + bb, 0.f);
      }
    }
  }
}

extern "C" void kernel_launch(void* const* d_in, const int* in_sizes, int n_in,
                              void* d_out, int out_size, void* d_ws, size_t ws_size,
                              hipStream_t stream) {
  const float* user = (const float*)d_in[0];
  const float* item = (const float*)d_in[1];
  const int*   r    = (const int*)d_in[2];
  const float* c    = (const float*)d_in[3];
  const float* Wu   = (const float*)d_in[4];
  const float* bu   = (const float*)d_in[5];
  const float* Wv   = (const float*)d_in[6];
  const float* bv   = (const float*)d_in[7];
  const float* Wl   = (const float*)d_in[8];
  const float* bl   = (const float*)d_in[9];
  float* out = (float*)d_out;

  int* bucket = (int*)d_ws;          // NB ints
  int* cnt    = bucket + NB;         // KREL
  int* cursor = cnt + KREL;          // KREL
  int* aoff   = cursor + KREL;       // KREL+1

  hipMemsetAsync(bucket, 0xFF, (size_t)NB * sizeof(int), stream);
  hipMemsetAsync(cnt, 0, KREL * sizeof(int), stream);

  const int nthr = 256;
  hist_kernel<<<(N_ROWS + nthr - 1) / nthr, nthr, 0, stream>>>(r, cnt);
  offs_kernel<<<1, 1, 0, stream>>>(cnt, aoff, cursor);
  scat_kernel<<<(N_ROWS + nthr - 1) / nthr, nthr, 0, stream>>>(r, bucket, cursor);
  gcn_main<<<NTILES, 256, 0, stream>>>(user, item, c, Wu, bu, Wv, bv, Wl, bl,
                                       bucket, aoff, out);
}